// Round 13
// baseline (1289.398 us; speedup 1.0000x reference)
//
#include <hip/hip_runtime.h>
#include <hip/hip_bf16.h>
#include <math.h>

typedef float f32x4 __attribute__((ext_vector_type(4)));
typedef short s16x8 __attribute__((ext_vector_type(8)));

// ---- workspace layout (bytes) ---- total < 1 MB
static const long long OFF_W2  = 0LL;        // bf16 [9][128][64]  = 147,456 B
static const long long OFF_W3  = 147456LL;   // bf16 [9][256][128] = 589,824 B
static const long long OFF_AB1 = 737280LL;   // float2 [64]
static const long long OFF_AB2 = 737792LL;   // float2 [128]
static const long long OFF_AB3 = 738816LL;   // float2 [256]
static const long long OFF_Q   = 740864LL;   // float  [8]: A0,A1,C0,C1,cos(qp1),fc1b1

__device__ inline unsigned short f2bfu(float f) {
    __hip_bfloat16 h = __float2bfloat16(f);
    unsigned short u;
    __builtin_memcpy(&u, &h, 2);
    return u;
}

// ---------------- prep: weight transpose to [kykx][oc][ic] bf16 + BN folding + fc fold ----------------
__global__ __launch_bounds__(256) void prep_k(
    const float* __restrict__ c2w, const float* __restrict__ c3w,
    const float* __restrict__ c1b, const float* __restrict__ g1, const float* __restrict__ b1,
    const float* __restrict__ m1, const float* __restrict__ v1,
    const float* __restrict__ c2b, const float* __restrict__ g2, const float* __restrict__ b2,
    const float* __restrict__ m2, const float* __restrict__ v2,
    const float* __restrict__ c3b, const float* __restrict__ g3, const float* __restrict__ b3,
    const float* __restrict__ m3, const float* __restrict__ v3,
    const float* __restrict__ fc1b, const float* __restrict__ qp,
    const float* __restrict__ fc2w, const float* __restrict__ fc2b,
    const float* __restrict__ fc3w, const float* __restrict__ fc3b,
    short* __restrict__ wT2, short* __restrict__ wT3,
    float2* __restrict__ ab1, float2* __restrict__ ab2, float2* __restrict__ ab3,
    float* __restrict__ qc)
{
    int tid = blockIdx.x * 256 + threadIdx.x;
    if (tid < 73728) {                       // 9*128*64
        int ic = tid & 63, oc = (tid >> 6) & 127, k = tid >> 13;
        wT2[tid] = (short)f2bfu(c2w[(oc * 64 + ic) * 9 + k]);
    }
    if (tid < 294912) {                      // 9*256*128
        int ic = tid & 127, oc = (tid >> 7) & 255, k = tid >> 15;
        wT3[tid] = (short)f2bfu(c3w[(oc * 128 + ic) * 9 + k]);
    }
    if (tid < 64) {
        float s = g1[tid] / sqrtf(v1[tid] + 1e-5f);
        ab1[tid] = make_float2(s, (c1b[tid] - m1[tid]) * s + b1[tid]);
    } else if (tid < 192) {
        int c = tid - 64;
        float s = g2[c] / sqrtf(v2[c] + 1e-5f);
        ab2[c] = make_float2(s, (c2b[c] - m2[c]) * s + b2[c]);
    } else if (tid < 448) {
        int c = tid - 192;
        float s = g3[c] / sqrtf(v3[c] + 1e-5f);
        ab3[c] = make_float2(s, (c3b[c] - m3[c]) * s + b3[c]);
    } else if (tid == 448) {
        float A0 = 0.f, A1 = 0.f, B0 = 0.f, B1 = 0.f;
        for (int k = 0; k < 128; ++k) {
            float f2 = fc2w[k], fb = fc2b[k];
            A0 += fc3w[k] * f2;        B0 += fc3w[k] * fb;
            A1 += fc3w[128 + k] * f2;  B1 += fc3w[128 + k] * fb;
        }
        qc[0] = A0; qc[1] = A1;
        qc[2] = B0 + fc3b[0]; qc[3] = B1 + fc3b[1];
        qc[4] = cosf(qp[1]);  qc[5] = fc1b[1];
    }
}

// ---------------- fused: R12 skeleton + conv1 via MFMA ----------------
// R12 base (48 KB LDS union, (512,6) -> 3 blocks/CU, single-pass conv2 acc[14], 929us best).
// ONE change: stage A's ~880 scalar FMAs/lane (pure-VALU phase between barriers while the MFMA
// pipe idles at 23%) replaced by 16x16x32 MFMA: K=9 fits one MFMA (no accumulation); BN affine
// folded in (weights pre-scaled by aa; bb placed in the k=9 slot vs constant-1.0 B element).
// Positions quad-encoded (R8's verified scheme): pool = shfl_xor 1,2. 49 tiles x 4 oc-tiles.
// Stage-A wave issue ~1300 -> ~750 instrs; moves work from 40%-busy VALU to 23%-busy MFMA pipe.
__global__ __launch_bounds__(512, 6) void fused_k(
    const float* __restrict__ x, const float* __restrict__ c1w,
    const float2* __restrict__ ab1, const float2* __restrict__ ab2,
    const float2* __restrict__ ab3,
    const short* __restrict__ wT2, const short* __restrict__ wT3,
    const float* __restrict__ fc1w, const float* __restrict__ qc,
    float* __restrict__ out)
{
    __shared__ short xs2[16 * 16 * 64];      // conv2 input tile [y][x][8 blk][8 ic], swizzled (32 KB)
    __shared__ short u3[8 * 8 * 128];        // 16 KB UNION: stage-A xt / conv3 xs3 / final red

    float (*xt)[32] = (float (*)[32])u3;     // padded 28x28 input at [1..28][1..28]
    short* xs3 = u3;                         // conv3 input tile [y][x][16 blk][8 ic], swizzled
    float* red = (float*)u3;                 // 8 floats, valid only after post-conv3 barrier

    int b = blockIdx.x, t = threadIdx.x;
    int lane = t & 63, wid = t >> 6;
    int n16 = lane & 15, quad = lane >> 4;
    int dy = n16 >> 3, lx = n16 & 7;

    // ---- prefetch input into regs (hides HBM latency under zero-init) ----
    float xv0 = x[b * 784 + t];              // t < 512 < 784 always valid
    float xv1 = (t + 512 < 784) ? x[b * 784 + t + 512] : 0.f;

    // ---- build conv1 A-fragments (affine-folded): row oc = ot*16 + n16, k = quad*8 + j ----
    // k 0..8 = weights * aa ; k 9 = bb (bias slot, paired with constant-1.0 in B)
    s16x8 A1f[4];
#pragma unroll
    for (int ot = 0; ot < 4; ++ot) {
        float2 ab = ab1[ot * 16 + n16];
        s16x8 a = {0, 0, 0, 0, 0, 0, 0, 0};
        if (quad == 0) {
#pragma unroll
            for (int j = 0; j < 8; ++j)
                a[j] = (short)f2bfu(c1w[(ot * 16 + n16) * 9 + j] * ab.x);
        } else if (quad == 1) {
            a[0] = (short)f2bfu(c1w[(ot * 16 + n16) * 9 + 8] * ab.x);
            a[1] = (short)f2bfu(ab.y);
        }
        A1f[ot] = a;
    }

    // ---- zero-init (xs2 fully; xt incl. borders) ----
    for (int i = t; i < 8192; i += 512) ((unsigned*)xs2)[i] = 0u;
    for (int i = t; i < 960;  i += 512) ((unsigned*)u3)[i] = 0u;
    __syncthreads();

    // ---- stage A: store input to xt ----
    xt[t / 28 + 1][t % 28 + 1] = xv0;
    if (t + 512 < 784) xt[(t + 512) / 28 + 1][(t + 512) % 28 + 1] = xv1;
    __syncthreads();

    // ---- stage A: conv1 via MFMA. 49 tiles x 16 pos-slots (4 pool-quads each) ----
    // slot s = lane&15: quad q = T*4 + (s>>2); within-quad dy'=(s>>1)&1, dx'=s&1.
    // B col = s, k = quad*8+j: quad0 = patch k 0..7, quad1 j0 = patch k8, j1 = 1.0 (bias).
    for (int T = wid; T < 49; T += 8) {
        int q = T * 4 + (n16 >> 2);
        int qy = q / 14, qx = q - qy * 14;
        int yy = 2 * qy + ((n16 >> 1) & 1);
        int xx = 2 * qx + (n16 & 1);
        const float* pxt = &xt[yy][xx];
        s16x8 Bf = {0, 0, 0, 0, 0, 0, 0, 0};
        if (quad == 0) {
            Bf[0] = (short)f2bfu(pxt[0]);
            Bf[1] = (short)f2bfu(pxt[1]);
            Bf[2] = (short)f2bfu(pxt[2]);
            Bf[3] = (short)f2bfu(pxt[32]);
            Bf[4] = (short)f2bfu(pxt[33]);
            Bf[5] = (short)f2bfu(pxt[34]);
            Bf[6] = (short)f2bfu(pxt[64]);
            Bf[7] = (short)f2bfu(pxt[65]);
        } else if (quad == 1) {
            Bf[0] = (short)f2bfu(pxt[66]);
            Bf[1] = (short)0x3F80;           // bf16(1.0) -> bias slot k=9
        }

        f32x4 z4 = {0.f, 0.f, 0.f, 0.f};
        bool wr = ((n16 & 3) == 0);          // one writer lane per pool-quad per quad-row
        int wb = (qy + 1) * 16 + (qx + 1);   // padded position
        int blkb = (qx + 1) & 7;
#pragma unroll
        for (int ot = 0; ot < 4; ++ot) {
            // D: col = n16 (pos-slot), row = quad*4 + r (oc within tile) -> oc = ot*16+quad*4+r
            f32x4 acc = __builtin_amdgcn_mfma_f32_16x16x32_bf16(A1f[ot], Bf, z4, 0, 0, 0);
            unsigned short us[4];
#pragma unroll
            for (int r = 0; r < 4; ++r) {
                float v = acc[r];                    // BN already applied via folded A
                v = fmaxf(v, __shfl_xor(v, 1));      // pool dx
                v = fmaxf(v, __shfl_xor(v, 2));      // pool dy
                us[r] = f2bfu(fmaxf(v, 0.f));        // ReLU (max-pool commutes: scale>0)
            }
            if (wr) {
                int oc0 = ot * 16 + quad * 4;
                uint2 pk;
                pk.x = (unsigned)us[0] | ((unsigned)us[1] << 16);
                pk.y = (unsigned)us[2] | ((unsigned)us[3] << 16);
                int blk = (oc0 >> 3) ^ blkb;         // XOR swizzle by padded column
                *(uint2*)&xs2[((wb * 8) + blk) * 8 + (oc0 & 7)] = pk;
            }
        }
    }
    __syncthreads();
    // xt is DEAD; u3 becomes xs3. Zero only the halo (row 0 cols 0..7, col 0 rows 1..7).
    for (int i = t; i < 960; i += 512) {     // 15 pos x 64 u32
        int pos = i >> 6, w = i & 63;
        int yy = (pos < 8) ? 0 : pos - 7;
        int xx = (pos < 8) ? pos : 0;
        ((unsigned*)xs3)[(yy * 8 + xx) * 64 + w] = 0u;
    }

    // ---- stage B: conv2 (64->128) via MFMA + BN + ReLU + pool -> xs3 (single pass, acc[14]) ----
    {
        f32x4 acc[14];
        f32x4 z = {0.f, 0.f, 0.f, 0.f};
#pragma unroll
        for (int nt = 0; nt < 14; ++nt) acc[nt] = z;

#pragma unroll 1
        for (int kykx = 0; kykx < 9; ++kykx) {
            int ky = kykx / 3, kx = kykx - 3 * ky;
            int dyky = dy + ky;
            int xc0 = lx + kx;                       // padded col, cb=0
            int xc1 = xc0 + 8; if (xc1 > 15) xc1 = 15;  // cb=1; lanes lx>=6 discarded later
#pragma unroll
            for (int kk = 0; kk < 2; ++kk) {
                s16x8 A = *(const s16x8*)(wT2 + ((kykx * 128 + wid * 16 + n16) * 64 + kk * 32 + quad * 8));
                int bi = kk * 4 + quad;
#pragma unroll
                for (int nt = 0; nt < 14; ++nt) {
                    int ry = nt >> 1, cb = nt & 1;
                    int y_in = 2 * ry + dyky;
                    int x_in = cb ? xc1 : xc0;
                    int blk = bi ^ (x_in & 7);
                    s16x8 B = *(const s16x8*)&xs2[((y_in * 16 + x_in) * 8 + blk) * 8];
                    acc[nt] = __builtin_amdgcn_mfma_f32_16x16x32_bf16(A, B, acc[nt], 0, 0, 0);
                }
            }
        }

        // epilogue: affine -> pool (shfl 1,8) -> ReLU -> store into xs3 (swizzled)
        int m = lx >> 1;
        bool keep = (dy == 0) && ((lx & 1) == 0);
        int oc0 = wid * 16 + quad * 4;
        float2 abv[4];
#pragma unroll
        for (int r = 0; r < 4; ++r) abv[r] = ab2[oc0 + r];
#pragma unroll
        for (int nt = 0; nt < 14; ++nt) {
            int ry = nt >> 1, cb = nt & 1;
            int xp = cb * 4 + m;
            float pv[4];
#pragma unroll
            for (int r = 0; r < 4; ++r) {
                float v = acc[nt][r] * abv[r].x + abv[r].y;
                v = fmaxf(v, __shfl_xor(v, 1));
                v = fmaxf(v, __shfl_xor(v, 8));
                pv[r] = fmaxf(v, 0.f);
            }
            if (keep && xp < 7) {
                uint2 pk;
                pk.x = (unsigned)f2bfu(pv[0]) | ((unsigned)f2bfu(pv[1]) << 16);
                pk.y = (unsigned)f2bfu(pv[2]) | ((unsigned)f2bfu(pv[3]) << 16);
                int blk3 = (oc0 >> 3) ^ (((xp + 1) & 7) << 1);
                *(uint2*)&xs3[(((ry + 1) * 8 + (xp + 1)) * 16 + blk3) * 8 + (oc0 & 7)] = pk;
            }
        }
    }
    __syncthreads();

    // ---- stage C: conv3 (128->256) via MFMA + BN + ReLU + pool + fc1[row1] dot ----
    f32x4 acc[2][3];                         // 2 oc-tiles per wave (8 waves x 2 = 16 tiles = 256 oc)
    f32x4 z = {0.f, 0.f, 0.f, 0.f};
#pragma unroll
    for (int ml = 0; ml < 2; ++ml)
#pragma unroll
        for (int nt = 0; nt < 3; ++nt) acc[ml][nt] = z;

#pragma unroll 1
    for (int kykx = 0; kykx < 9; ++kykx) {
        int ky = kykx / 3, kx = kykx - 3 * ky;
        int dyky = dy + ky;
        int x_in = lx + kx; if (x_in > 7) x_in = 7;   // lanes lx>=6 discarded later
#pragma unroll
        for (int kk = 0; kk < 4; ++kk) {
            s16x8 A[2];
#pragma unroll
            for (int ml = 0; ml < 2; ++ml)
                A[ml] = *(const s16x8*)(wT3 + ((kykx * 256 + (wid * 2 + ml) * 16 + n16) * 128 + kk * 32 + quad * 8));
            int bi = kk * 4 + quad;
            int blk = bi ^ ((x_in & 7) << 1);
#pragma unroll
            for (int nt = 0; nt < 3; ++nt) {
                int y_in = 2 * nt + dyky;
                s16x8 B = *(const s16x8*)&xs3[((y_in * 8 + x_in) * 16 + blk) * 8];
#pragma unroll
                for (int ml = 0; ml < 2; ++ml)
                    acc[ml][nt] = __builtin_amdgcn_mfma_f32_16x16x32_bf16(A[ml], B, acc[ml][nt], 0, 0, 0);
            }
        }
    }
    __syncthreads();                         // all xs3 reads done -> u3 reusable as red

    // epilogue: affine -> pool -> relu -> dot with fc1_w row 1
    float vacc = 0.f;
    int m = lx >> 1;
    bool keep = (dy == 0) && ((lx & 1) == 0) && (m < 3);
    const float* fc1w1 = fc1w + 2304;        // row 1 (only row that matters)
#pragma unroll
    for (int ml = 0; ml < 2; ++ml) {
        int oc0 = (wid * 2 + ml) * 16 + quad * 4;
        float2 abv[4];
#pragma unroll
        for (int r = 0; r < 4; ++r) abv[r] = ab3[oc0 + r];
#pragma unroll
        for (int nt = 0; nt < 3; ++nt) {
#pragma unroll
            for (int r = 0; r < 4; ++r) {
                float v = acc[ml][nt][r] * abv[r].x + abv[r].y;
                v = fmaxf(v, __shfl_xor(v, 1));
                v = fmaxf(v, __shfl_xor(v, 8));
                v = fmaxf(v, 0.f);
                if (keep) vacc += v * fc1w1[(oc0 + r) * 9 + nt * 3 + m];
            }
        }
    }
#pragma unroll
    for (int s = 1; s < 64; s <<= 1) vacc += __shfl_xor(vacc, s);
    if (lane == 0) red[wid] = vacc;
    __syncthreads();
    if (t == 0) {
        float v = red[0] + red[1] + red[2] + red[3]
                + red[4] + red[5] + red[6] + red[7] + qc[5];
        // quantum circuit closed form: <Z0 Z1> = cos(h[:,1]) * cos(qp[1])
        float q = cosf(v) * qc[4];
        float l0 = q * qc[0] + qc[2];
        float l1 = q * qc[1] + qc[3];
        float mx = fmaxf(l0, l1);
        float lse = mx + logf(__expf(l0 - mx) + __expf(l1 - mx));
        out[b * 2 + 0] = l0 - lse;
        out[b * 2 + 1] = l1 - lse;
    }
}

extern "C" void kernel_launch(void* const* d_in, const int* in_sizes, int n_in,
                              void* d_out, int out_size, void* d_ws, size_t ws_size,
                              hipStream_t stream)
{
    const float* x    = (const float*)d_in[0];
    const float* c1w  = (const float*)d_in[1];
    const float* c1b  = (const float*)d_in[2];
    const float* c2w  = (const float*)d_in[3];
    const float* c2b  = (const float*)d_in[4];
    const float* c3w  = (const float*)d_in[5];
    const float* c3b  = (const float*)d_in[6];
    const float* g1   = (const float*)d_in[7];
    const float* b1   = (const float*)d_in[8];
    const float* m1   = (const float*)d_in[9];
    const float* v1   = (const float*)d_in[10];
    const float* g2   = (const float*)d_in[11];
    const float* b2   = (const float*)d_in[12];
    const float* m2   = (const float*)d_in[13];
    const float* v2   = (const float*)d_in[14];
    const float* g3   = (const float*)d_in[15];
    const float* b3   = (const float*)d_in[16];
    const float* m3   = (const float*)d_in[17];
    const float* v3   = (const float*)d_in[18];
    const float* fc1w = (const float*)d_in[19];
    const float* fc1b = (const float*)d_in[20];
    const float* qp   = (const float*)d_in[21];
    const float* fc2w = (const float*)d_in[22];
    const float* fc2b = (const float*)d_in[23];
    const float* fc3w = (const float*)d_in[24];
    const float* fc3b = (const float*)d_in[25];
    float* out = (float*)d_out;
    char* ws = (char*)d_ws;

    short*  wT2 = (short*)(ws + OFF_W2);
    short*  wT3 = (short*)(ws + OFF_W3);
    float2* ab1 = (float2*)(ws + OFF_AB1);
    float2* ab2 = (float2*)(ws + OFF_AB2);
    float2* ab3 = (float2*)(ws + OFF_AB3);
    float*  qc  = (float*)(ws + OFF_Q);

    int B = in_sizes[0] / 784;               // 8192

    prep_k<<<1152, 256, 0, stream>>>(c2w, c3w, c1b, g1, b1, m1, v1,
                                     c2b, g2, b2, m2, v2, c3b, g3, b3, m3, v3,
                                     fc1b, qp, fc2w, fc2b, fc3w, fc3b,
                                     wT2, wT3, ab1, ab2, ab3, qc);
    fused_k<<<B, 512, 0, stream>>>(x, c1w, ab1, ab2, ab3, wT2, wT3, fc1w, qc, out);
}

// Round 14
// 1002.926 us; speedup vs baseline: 1.2856x; 1.2856x over previous
//
#include <hip/hip_runtime.h>
#include <hip/hip_bf16.h>
#include <math.h>

typedef float f32x4 __attribute__((ext_vector_type(4)));
typedef short s16x8 __attribute__((ext_vector_type(8)));

// ---- workspace layout (bytes) ---- total < 1 MB
static const long long OFF_W2  = 0LL;        // bf16 [9][128][64]  = 147,456 B
static const long long OFF_W3  = 147456LL;   // bf16 [9][256][128] = 589,824 B
static const long long OFF_AB1 = 737280LL;   // float2 [64]
static const long long OFF_AB2 = 737792LL;   // float2 [128]
static const long long OFF_AB3 = 738816LL;   // float2 [256]
static const long long OFF_Q   = 740864LL;   // float  [8]: A0,A1,C0,C1,cos(qp1),fc1b1

__device__ inline unsigned short f2bfu(float f) {
    __hip_bfloat16 h = __float2bfloat16(f);
    unsigned short u;
    __builtin_memcpy(&u, &h, 2);
    return u;
}

// ---------------- prep: weight transpose to [kykx][oc][ic] bf16 + BN folding + fc fold ----------------
__global__ __launch_bounds__(256) void prep_k(
    const float* __restrict__ c2w, const float* __restrict__ c3w,
    const float* __restrict__ c1b, const float* __restrict__ g1, const float* __restrict__ b1,
    const float* __restrict__ m1, const float* __restrict__ v1,
    const float* __restrict__ c2b, const float* __restrict__ g2, const float* __restrict__ b2,
    const float* __restrict__ m2, const float* __restrict__ v2,
    const float* __restrict__ c3b, const float* __restrict__ g3, const float* __restrict__ b3,
    const float* __restrict__ m3, const float* __restrict__ v3,
    const float* __restrict__ fc1b, const float* __restrict__ qp,
    const float* __restrict__ fc2w, const float* __restrict__ fc2b,
    const float* __restrict__ fc3w, const float* __restrict__ fc3b,
    short* __restrict__ wT2, short* __restrict__ wT3,
    float2* __restrict__ ab1, float2* __restrict__ ab2, float2* __restrict__ ab3,
    float* __restrict__ qc)
{
    int tid = blockIdx.x * 256 + threadIdx.x;
    if (tid < 73728) {                       // 9*128*64
        int ic = tid & 63, oc = (tid >> 6) & 127, k = tid >> 13;
        wT2[tid] = (short)f2bfu(c2w[(oc * 64 + ic) * 9 + k]);
    }
    if (tid < 294912) {                      // 9*256*128
        int ic = tid & 127, oc = (tid >> 7) & 255, k = tid >> 15;
        wT3[tid] = (short)f2bfu(c3w[(oc * 128 + ic) * 9 + k]);
    }
    if (tid < 64) {
        float s = g1[tid] / sqrtf(v1[tid] + 1e-5f);
        ab1[tid] = make_float2(s, (c1b[tid] - m1[tid]) * s + b1[tid]);
    } else if (tid < 192) {
        int c = tid - 64;
        float s = g2[c] / sqrtf(v2[c] + 1e-5f);
        ab2[c] = make_float2(s, (c2b[c] - m2[c]) * s + b2[c]);
    } else if (tid < 448) {
        int c = tid - 192;
        float s = g3[c] / sqrtf(v3[c] + 1e-5f);
        ab3[c] = make_float2(s, (c3b[c] - m3[c]) * s + b3[c]);
    } else if (tid == 448) {
        float A0 = 0.f, A1 = 0.f, B0 = 0.f, B1 = 0.f;
        for (int k = 0; k < 128; ++k) {
            float f2 = fc2w[k], fb = fc2b[k];
            A0 += fc3w[k] * f2;        B0 += fc3w[k] * fb;
            A1 += fc3w[128 + k] * f2;  B1 += fc3w[128 + k] * fb;
        }
        qc[0] = A0; qc[1] = A1;
        qc[2] = B0 + fc3b[0]; qc[3] = B1 + fc3b[1];
        qc[4] = cosf(qp[1]);  qc[5] = fc1b[1];
    }
}

// ---------------- fused: R12 (929us session best) + s_setprio around MFMA phases ----------------
// EXACT R12 structure: 48 KB LDS union, (512,6) -> 3 blocks/CU, low-pressure stage A (32 groups
// x 2 oc), single-pass conv2 acc[14], known mild spill (~177 MB WRITE, measured cheaper than any
// restructure that removes it). ONE change: s_setprio(1) around the conv2/conv3 MFMA loops.
// Mechanism (guide T5): 3 independent blocks/CU sit at DIFFERENT phases (stage-A VALU vs conv2
// MFMA); raising priority during MFMA lets the MFMA-phase block win issue arbitration vs the
// co-resident VALU-phase block -> higher matrix-pipe occupancy at zero resource cost.
__global__ __launch_bounds__(512, 6) void fused_k(
    const float* __restrict__ x, const float* __restrict__ c1w,
    const float2* __restrict__ ab1, const float2* __restrict__ ab2,
    const float2* __restrict__ ab3,
    const short* __restrict__ wT2, const short* __restrict__ wT3,
    const float* __restrict__ fc1w, const float* __restrict__ qc,
    float* __restrict__ out)
{
    __shared__ short xs2[16 * 16 * 64];      // conv2 input tile [y][x][8 blk][8 ic], swizzled (32 KB)
    __shared__ short u3[8 * 8 * 128];        // 16 KB UNION: stage-A xt / conv3 xs3 / final red

    float (*xt)[32] = (float (*)[32])u3;     // padded 28x28 input at [1..28][1..28]
    short* xs3 = u3;                         // conv3 input tile [y][x][16 blk][8 ic], swizzled
    float* red = (float*)u3;                 // 8 floats, valid only after post-conv3 barrier

    int b = blockIdx.x, t = threadIdx.x;

    // ---- zero-init (xs2 fully; xt incl. borders) ----
    for (int i = t; i < 8192; i += 512) ((unsigned*)xs2)[i] = 0u;
    for (int i = t; i < 960;  i += 512) ((unsigned*)u3)[i] = 0u;
    __syncthreads();

    // ---- stage A: load input, conv1 (VALU fp32) + BN + ReLU + 2x2 pool -> xs2 ----
    for (int i = t; i < 784; i += 512) xt[i / 28 + 1][i % 28 + 1] = x[b * 784 + i];

    int ocg2 = t & 31;                       // 32 groups of 2 output channels
    float wr[2][9];
    float2 abr[2];
#pragma unroll
    for (int c = 0; c < 2; ++c) {
#pragma unroll
        for (int k = 0; k < 9; ++k) wr[c][k] = c1w[(ocg2 * 2 + c) * 9 + k];
        abr[c] = ab1[ocg2 * 2 + c];
    }
    __syncthreads();

    int posb = t >> 5;                       // 0..15
    for (int p = posb; p < 196; p += 16) {
        int py = p / 14, px = p % 14;
        int y0 = 2 * py, x0 = 2 * px;
        float patch[4][4];
#pragma unroll
        for (int i = 0; i < 4; ++i)
#pragma unroll
            for (int j = 0; j < 4; ++j) patch[i][j] = xt[y0 + i][x0 + j];

        unsigned short ub[2];
#pragma unroll
        for (int c = 0; c < 2; ++c) {
            float a00 = 0.f, a01 = 0.f, a10 = 0.f, a11 = 0.f;
#pragma unroll
            for (int ky = 0; ky < 3; ++ky)
#pragma unroll
                for (int kx = 0; kx < 3; ++kx) {
                    float wv = wr[c][ky * 3 + kx];
                    a00 += patch[ky + 0][kx + 0] * wv;
                    a01 += patch[ky + 0][kx + 1] * wv;
                    a10 += patch[ky + 1][kx + 0] * wv;
                    a11 += patch[ky + 1][kx + 1] * wv;
                }
            float aa = abr[c].x, bb = abr[c].y;
            float v = fmaxf(fmaxf(a00 * aa + bb, a01 * aa + bb),
                            fmaxf(a10 * aa + bb, a11 * aa + bb));
            ub[c] = f2bfu(fmaxf(v, 0.f));
        }
        unsigned pk = (unsigned)ub[0] | ((unsigned)ub[1] << 16);
        int oc0 = ocg2 * 2;                  // ic-group g = oc0>>3 = ocg2>>2; within-block = oc0&7
        int blk = (ocg2 >> 2) ^ ((px + 1) & 7);   // XOR swizzle by padded column
        *(unsigned*)&xs2[((((py + 1) * 16) + (px + 1)) * 8 + blk) * 8 + (oc0 & 7)] = pk;
    }
    __syncthreads();
    // xt is DEAD; u3 becomes xs3. Zero only the halo (row 0 cols 0..7, col 0 rows 1..7).
    for (int i = t; i < 960; i += 512) {     // 15 pos x 64 u32
        int pos = i >> 6, w = i & 63;
        int yy = (pos < 8) ? 0 : pos - 7;
        int xx = (pos < 8) ? pos : 0;
        ((unsigned*)xs3)[(yy * 8 + xx) * 64 + w] = 0u;
    }

    // ---- stage B: conv2 (64->128) via MFMA + BN + ReLU + pool -> xs3 (single pass, acc[14]) ----
    int lane = t & 63, wid = t >> 6;         // wid 0..7, one 16-oc tile per wave
    int quad = lane >> 4, n16 = lane & 15;
    int dy = n16 >> 3, lx = n16 & 7;

    {
        f32x4 acc[14];
        f32x4 z = {0.f, 0.f, 0.f, 0.f};
#pragma unroll
        for (int nt = 0; nt < 14; ++nt) acc[nt] = z;

        __builtin_amdgcn_s_setprio(1);       // MFMA phase: win issue arbitration vs co-resident blocks
#pragma unroll 1
        for (int kykx = 0; kykx < 9; ++kykx) {
            int ky = kykx / 3, kx = kykx - 3 * ky;
            int dyky = dy + ky;
            int xc0 = lx + kx;                       // padded col, cb=0
            int xc1 = xc0 + 8; if (xc1 > 15) xc1 = 15;  // cb=1; lanes lx>=6 discarded later
#pragma unroll
            for (int kk = 0; kk < 2; ++kk) {
                s16x8 A = *(const s16x8*)(wT2 + ((kykx * 128 + wid * 16 + n16) * 64 + kk * 32 + quad * 8));
                int bi = kk * 4 + quad;
#pragma unroll
                for (int nt = 0; nt < 14; ++nt) {
                    int ry = nt >> 1, cb = nt & 1;
                    int y_in = 2 * ry + dyky;
                    int x_in = cb ? xc1 : xc0;
                    int blk = bi ^ (x_in & 7);
                    s16x8 B = *(const s16x8*)&xs2[((y_in * 16 + x_in) * 8 + blk) * 8];
                    acc[nt] = __builtin_amdgcn_mfma_f32_16x16x32_bf16(A, B, acc[nt], 0, 0, 0);
                }
            }
        }
        __builtin_amdgcn_s_setprio(0);

        // epilogue: affine -> pool (shfl 1,8) -> ReLU -> store into xs3 (swizzled)
        int m = lx >> 1;
        bool keep = (dy == 0) && ((lx & 1) == 0);
        int oc0 = wid * 16 + quad * 4;
        float2 abv[4];
#pragma unroll
        for (int r = 0; r < 4; ++r) abv[r] = ab2[oc0 + r];
#pragma unroll
        for (int nt = 0; nt < 14; ++nt) {
            int ry = nt >> 1, cb = nt & 1;
            int xp = cb * 4 + m;
            float pv[4];
#pragma unroll
            for (int r = 0; r < 4; ++r) {
                float v = acc[nt][r] * abv[r].x + abv[r].y;
                v = fmaxf(v, __shfl_xor(v, 1));
                v = fmaxf(v, __shfl_xor(v, 8));
                pv[r] = fmaxf(v, 0.f);
            }
            if (keep && xp < 7) {
                uint2 pk;
                pk.x = (unsigned)f2bfu(pv[0]) | ((unsigned)f2bfu(pv[1]) << 16);
                pk.y = (unsigned)f2bfu(pv[2]) | ((unsigned)f2bfu(pv[3]) << 16);
                int blk3 = (oc0 >> 3) ^ (((xp + 1) & 7) << 1);
                *(uint2*)&xs3[(((ry + 1) * 8 + (xp + 1)) * 16 + blk3) * 8 + (oc0 & 7)] = pk;
            }
        }
    }
    __syncthreads();

    // ---- stage C: conv3 (128->256) via MFMA + BN + ReLU + pool + fc1[row1] dot ----
    f32x4 acc[2][3];                         // 2 oc-tiles per wave (8 waves x 2 = 16 tiles = 256 oc)
    f32x4 z = {0.f, 0.f, 0.f, 0.f};
#pragma unroll
    for (int ml = 0; ml < 2; ++ml)
#pragma unroll
        for (int nt = 0; nt < 3; ++nt) acc[ml][nt] = z;

    __builtin_amdgcn_s_setprio(1);           // MFMA phase
#pragma unroll 1
    for (int kykx = 0; kykx < 9; ++kykx) {
        int ky = kykx / 3, kx = kykx - 3 * ky;
        int dyky = dy + ky;
        int x_in = lx + kx; if (x_in > 7) x_in = 7;   // lanes lx>=6 discarded later
#pragma unroll
        for (int kk = 0; kk < 4; ++kk) {
            s16x8 A[2];
#pragma unroll
            for (int ml = 0; ml < 2; ++ml)
                A[ml] = *(const s16x8*)(wT3 + ((kykx * 256 + (wid * 2 + ml) * 16 + n16) * 128 + kk * 32 + quad * 8));
            int bi = kk * 4 + quad;
            int blk = bi ^ ((x_in & 7) << 1);
#pragma unroll
            for (int nt = 0; nt < 3; ++nt) {
                int y_in = 2 * nt + dyky;
                s16x8 B = *(const s16x8*)&xs3[((y_in * 8 + x_in) * 16 + blk) * 8];
#pragma unroll
                for (int ml = 0; ml < 2; ++ml)
                    acc[ml][nt] = __builtin_amdgcn_mfma_f32_16x16x32_bf16(A[ml], B, acc[ml][nt], 0, 0, 0);
            }
        }
    }
    __builtin_amdgcn_s_setprio(0);
    __syncthreads();                         // all xs3 reads done -> u3 reusable as red

    // epilogue: affine -> pool -> relu -> dot with fc1_w row 1
    float vacc = 0.f;
    int m = lx >> 1;
    bool keep = (dy == 0) && ((lx & 1) == 0) && (m < 3);
    const float* fc1w1 = fc1w + 2304;        // row 1 (only row that matters)
#pragma unroll
    for (int ml = 0; ml < 2; ++ml) {
        int oc0 = (wid * 2 + ml) * 16 + quad * 4;
        float2 abv[4];
#pragma unroll
        for (int r = 0; r < 4; ++r) abv[r] = ab3[oc0 + r];
#pragma unroll
        for (int nt = 0; nt < 3; ++nt) {
#pragma unroll
            for (int r = 0; r < 4; ++r) {
                float v = acc[ml][nt][r] * abv[r].x + abv[r].y;
                v = fmaxf(v, __shfl_xor(v, 1));
                v = fmaxf(v, __shfl_xor(v, 8));
                v = fmaxf(v, 0.f);
                if (keep) vacc += v * fc1w1[(oc0 + r) * 9 + nt * 3 + m];
            }
        }
    }
#pragma unroll
    for (int s = 1; s < 64; s <<= 1) vacc += __shfl_xor(vacc, s);
    if (lane == 0) red[wid] = vacc;
    __syncthreads();
    if (t == 0) {
        float v = red[0] + red[1] + red[2] + red[3]
                + red[4] + red[5] + red[6] + red[7] + qc[5];
        // quantum circuit closed form: <Z0 Z1> = cos(h[:,1]) * cos(qp[1])
        float q = cosf(v) * qc[4];
        float l0 = q * qc[0] + qc[2];
        float l1 = q * qc[1] + qc[3];
        float mx = fmaxf(l0, l1);
        float lse = mx + logf(__expf(l0 - mx) + __expf(l1 - mx));
        out[b * 2 + 0] = l0 - lse;
        out[b * 2 + 1] = l1 - lse;
    }
}

extern "C" void kernel_launch(void* const* d_in, const int* in_sizes, int n_in,
                              void* d_out, int out_size, void* d_ws, size_t ws_size,
                              hipStream_t stream)
{
    const float* x    = (const float*)d_in[0];
    const float* c1w  = (const float*)d_in[1];
    const float* c1b  = (const float*)d_in[2];
    const float* c2w  = (const float*)d_in[3];
    const float* c2b  = (const float*)d_in[4];
    const float* c3w  = (const float*)d_in[5];
    const float* c3b  = (const float*)d_in[6];
    const float* g1   = (const float*)d_in[7];
    const float* b1   = (const float*)d_in[8];
    const float* m1   = (const float*)d_in[9];
    const float* v1   = (const float*)d_in[10];
    const float* g2   = (const float*)d_in[11];
    const float* b2   = (const float*)d_in[12];
    const float* m2   = (const float*)d_in[13];
    const float* v2   = (const float*)d_in[14];
    const float* g3   = (const float*)d_in[15];
    const float* b3   = (const float*)d_in[16];
    const float* m3   = (const float*)d_in[17];
    const float* v3   = (const float*)d_in[18];
    const float* fc1w = (const float*)d_in[19];
    const float* fc1b = (const float*)d_in[20];
    const float* qp   = (const float*)d_in[21];
    const float* fc2w = (const float*)d_in[22];
    const float* fc2b = (const float*)d_in[23];
    const float* fc3w = (const float*)d_in[24];
    const float* fc3b = (const float*)d_in[25];
    float* out = (float*)d_out;
    char* ws = (char*)d_ws;

    short*  wT2 = (short*)(ws + OFF_W2);
    short*  wT3 = (short*)(ws + OFF_W3);
    float2* ab1 = (float2*)(ws + OFF_AB1);
    float2* ab2 = (float2*)(ws + OFF_AB2);
    float2* ab3 = (float2*)(ws + OFF_AB3);
    float*  qc  = (float*)(ws + OFF_Q);

    int B = in_sizes[0] / 784;               // 8192

    prep_k<<<1152, 256, 0, stream>>>(c2w, c3w, c1b, g1, b1, m1, v1,
                                     c2b, g2, b2, m2, v2, c3b, g3, b3, m3, v3,
                                     fc1b, qp, fc2w, fc2b, fc3w, fc3b,
                                     wT2, wT3, ab1, ab2, ab3, qc);
    fused_k<<<B, 512, 0, stream>>>(x, c1w, ab1, ab2, ab3, wT2, wT3, fc1w, qc, out);
}

// Round 15
// 940.822 us; speedup vs baseline: 1.3705x; 1.0660x over previous
//
#include <hip/hip_runtime.h>
#include <hip/hip_bf16.h>
#include <math.h>

typedef float f32x4 __attribute__((ext_vector_type(4)));
typedef short s16x8 __attribute__((ext_vector_type(8)));

// ---- workspace layout (bytes) ---- total < 1 MB
static const long long OFF_W2  = 0LL;        // bf16 [9][128][64]  = 147,456 B
static const long long OFF_W3  = 147456LL;   // bf16 [9][256][128] = 589,824 B
static const long long OFF_AB1 = 737280LL;   // float2 [64]
static const long long OFF_AB2 = 737792LL;   // float2 [128]
static const long long OFF_AB3 = 738816LL;   // float2 [256]
static const long long OFF_Q   = 740864LL;   // float  [8]: A0,A1,C0,C1,cos(qp1),fc1b1

__device__ inline unsigned short f2bfu(float f) {
    __hip_bfloat16 h = __float2bfloat16(f);
    unsigned short u;
    __builtin_memcpy(&u, &h, 2);
    return u;
}

// ---------------- prep: weight transpose to [kykx][oc][ic] bf16 + BN folding + fc fold ----------------
__global__ __launch_bounds__(256) void prep_k(
    const float* __restrict__ c2w, const float* __restrict__ c3w,
    const float* __restrict__ c1b, const float* __restrict__ g1, const float* __restrict__ b1,
    const float* __restrict__ m1, const float* __restrict__ v1,
    const float* __restrict__ c2b, const float* __restrict__ g2, const float* __restrict__ b2,
    const float* __restrict__ m2, const float* __restrict__ v2,
    const float* __restrict__ c3b, const float* __restrict__ g3, const float* __restrict__ b3,
    const float* __restrict__ m3, const float* __restrict__ v3,
    const float* __restrict__ fc1b, const float* __restrict__ qp,
    const float* __restrict__ fc2w, const float* __restrict__ fc2b,
    const float* __restrict__ fc3w, const float* __restrict__ fc3b,
    short* __restrict__ wT2, short* __restrict__ wT3,
    float2* __restrict__ ab1, float2* __restrict__ ab2, float2* __restrict__ ab3,
    float* __restrict__ qc)
{
    int tid = blockIdx.x * 256 + threadIdx.x;
    if (tid < 73728) {                       // 9*128*64
        int ic = tid & 63, oc = (tid >> 6) & 127, k = tid >> 13;
        wT2[tid] = (short)f2bfu(c2w[(oc * 64 + ic) * 9 + k]);
    }
    if (tid < 294912) {                      // 9*256*128
        int ic = tid & 127, oc = (tid >> 7) & 255, k = tid >> 15;
        wT3[tid] = (short)f2bfu(c3w[(oc * 128 + ic) * 9 + k]);
    }
    if (tid < 64) {
        float s = g1[tid] / sqrtf(v1[tid] + 1e-5f);
        ab1[tid] = make_float2(s, (c1b[tid] - m1[tid]) * s + b1[tid]);
    } else if (tid < 192) {
        int c = tid - 64;
        float s = g2[c] / sqrtf(v2[c] + 1e-5f);
        ab2[c] = make_float2(s, (c2b[c] - m2[c]) * s + b2[c]);
    } else if (tid < 448) {
        int c = tid - 192;
        float s = g3[c] / sqrtf(v3[c] + 1e-5f);
        ab3[c] = make_float2(s, (c3b[c] - m3[c]) * s + b3[c]);
    } else if (tid == 448) {
        float A0 = 0.f, A1 = 0.f, B0 = 0.f, B1 = 0.f;
        for (int k = 0; k < 128; ++k) {
            float f2 = fc2w[k], fb = fc2b[k];
            A0 += fc3w[k] * f2;        B0 += fc3w[k] * fb;
            A1 += fc3w[128 + k] * f2;  B1 += fc3w[128 + k] * fb;
        }
        qc[0] = A0; qc[1] = A1;
        qc[2] = B0 + fc3b[0]; qc[3] = B1 + fc3b[1];
        qc[4] = cosf(qp[1]);  qc[5] = fc1b[1];
    }
}

// ---------------- fused: R12 structure (929us best) + prologue trim, setprio reverted ----------------
// R12 base: 48 KB LDS union, (512,6) -> 3 blocks/CU, low-pressure stage A (32 groups x 2 oc),
// single-pass conv2 acc[14], known-cheap mild spill. R14's setprio REVERTED (measured -3.5%).
// NEW: (a) halo-only zero-init -- stage A fully overwrites xs2/xt interiors, so only zero the
// 60 xs2 halo positions (1920 u32) + 120 xt border floats instead of 9152 u32 (-78% of the
// serialized block prologue); (b) x prefetched into 2 regs before the zero loop so the HBM/L2
// load latency hides under it instead of stalling after the first barrier.
__global__ __launch_bounds__(512, 6) void fused_k(
    const float* __restrict__ x, const float* __restrict__ c1w,
    const float2* __restrict__ ab1, const float2* __restrict__ ab2,
    const float2* __restrict__ ab3,
    const short* __restrict__ wT2, const short* __restrict__ wT3,
    const float* __restrict__ fc1w, const float* __restrict__ qc,
    float* __restrict__ out)
{
    __shared__ short xs2[16 * 16 * 64];      // conv2 input tile [y][x][8 blk][8 ic], swizzled (32 KB)
    __shared__ short u3[8 * 8 * 128];        // 16 KB UNION: stage-A xt / conv3 xs3 / final red

    float (*xt)[32] = (float (*)[32])u3;     // padded 28x28 input at [1..28][1..28]
    short* xs3 = u3;                         // conv3 input tile [y][x][16 blk][8 ic], swizzled
    float* red = (float*)u3;                 // 8 floats, valid only after post-conv3 barrier

    int b = blockIdx.x, t = threadIdx.x;

    // ---- prefetch input (latency hides under halo zeroing) ----
    float xv0 = x[b * 784 + t];              // t < 512 < 784: always valid
    float xv1 = (t + 512 < 784) ? x[b * 784 + t + 512] : 0.f;

    // ---- halo-only zero-init ----
    // xs2 halo: positions with y in {0,15} or x in {0,15} -> 60 pos x 32 u32 = 1920 u32.
    for (int i = t; i < 1920; i += 512) {
        int pos = i >> 5, w = i & 31;
        int yy, xx;
        if (pos < 16)      { yy = 0;  xx = pos; }
        else if (pos < 32) { yy = 15; xx = pos - 16; }
        else { int q = pos - 32; yy = 1 + (q >> 1); xx = (q & 1) ? 15 : 0; }
        ((unsigned*)xs2)[(yy * 16 + xx) * 32 + w] = 0u;
    }
    // xt halo: row 0 (32), row 29 (32), col 0 rows 1..28 (28), col 29 rows 1..28 (28) = 120 floats.
    if (t < 120) {
        int yy, xx;
        if (t < 32)      { yy = 0;  xx = t; }
        else if (t < 64) { yy = 29; xx = t - 32; }
        else if (t < 92) { yy = 1 + (t - 64); xx = 0; }
        else             { yy = 1 + (t - 92); xx = 29; }
        xt[yy][xx] = 0.f;
    }
    __syncthreads();

    // ---- stage A: store input, load conv1 weights ----
    xt[t / 28 + 1][t % 28 + 1] = xv0;
    if (t + 512 < 784) xt[(t + 512) / 28 + 1][(t + 512) % 28 + 1] = xv1;

    int ocg2 = t & 31;                       // 32 groups of 2 output channels
    float wr[2][9];
    float2 abr[2];
#pragma unroll
    for (int c = 0; c < 2; ++c) {
#pragma unroll
        for (int k = 0; k < 9; ++k) wr[c][k] = c1w[(ocg2 * 2 + c) * 9 + k];
        abr[c] = ab1[ocg2 * 2 + c];
    }
    __syncthreads();

    int posb = t >> 5;                       // 0..15
    for (int p = posb; p < 196; p += 16) {
        int py = p / 14, px = p % 14;
        int y0 = 2 * py, x0 = 2 * px;
        float patch[4][4];
#pragma unroll
        for (int i = 0; i < 4; ++i)
#pragma unroll
            for (int j = 0; j < 4; ++j) patch[i][j] = xt[y0 + i][x0 + j];

        unsigned short ub[2];
#pragma unroll
        for (int c = 0; c < 2; ++c) {
            float a00 = 0.f, a01 = 0.f, a10 = 0.f, a11 = 0.f;
#pragma unroll
            for (int ky = 0; ky < 3; ++ky)
#pragma unroll
                for (int kx = 0; kx < 3; ++kx) {
                    float wv = wr[c][ky * 3 + kx];
                    a00 += patch[ky + 0][kx + 0] * wv;
                    a01 += patch[ky + 0][kx + 1] * wv;
                    a10 += patch[ky + 1][kx + 0] * wv;
                    a11 += patch[ky + 1][kx + 1] * wv;
                }
            float aa = abr[c].x, bb = abr[c].y;
            float v = fmaxf(fmaxf(a00 * aa + bb, a01 * aa + bb),
                            fmaxf(a10 * aa + bb, a11 * aa + bb));
            ub[c] = f2bfu(fmaxf(v, 0.f));
        }
        unsigned pk = (unsigned)ub[0] | ((unsigned)ub[1] << 16);
        int oc0 = ocg2 * 2;                  // ic-group g = oc0>>3 = ocg2>>2; within-block = oc0&7
        int blk = (ocg2 >> 2) ^ ((px + 1) & 7);   // XOR swizzle by padded column
        *(unsigned*)&xs2[((((py + 1) * 16) + (px + 1)) * 8 + blk) * 8 + (oc0 & 7)] = pk;
    }
    __syncthreads();
    // xt is DEAD; u3 becomes xs3. Zero only the halo (row 0 cols 0..7, col 0 rows 1..7).
    for (int i = t; i < 960; i += 512) {     // 15 pos x 64 u32
        int pos = i >> 6, w = i & 63;
        int yy = (pos < 8) ? 0 : pos - 7;
        int xx = (pos < 8) ? pos : 0;
        ((unsigned*)xs3)[(yy * 8 + xx) * 64 + w] = 0u;
    }

    // ---- stage B: conv2 (64->128) via MFMA + BN + ReLU + pool -> xs3 (single pass, acc[14]) ----
    int lane = t & 63, wid = t >> 6;         // wid 0..7, one 16-oc tile per wave
    int quad = lane >> 4, n16 = lane & 15;
    int dy = n16 >> 3, lx = n16 & 7;

    {
        f32x4 acc[14];
        f32x4 z = {0.f, 0.f, 0.f, 0.f};
#pragma unroll
        for (int nt = 0; nt < 14; ++nt) acc[nt] = z;

#pragma unroll 1
        for (int kykx = 0; kykx < 9; ++kykx) {
            int ky = kykx / 3, kx = kykx - 3 * ky;
            int dyky = dy + ky;
            int xc0 = lx + kx;                       // padded col, cb=0
            int xc1 = xc0 + 8; if (xc1 > 15) xc1 = 15;  // cb=1; lanes lx>=6 discarded later
#pragma unroll
            for (int kk = 0; kk < 2; ++kk) {
                s16x8 A = *(const s16x8*)(wT2 + ((kykx * 128 + wid * 16 + n16) * 64 + kk * 32 + quad * 8));
                int bi = kk * 4 + quad;
#pragma unroll
                for (int nt = 0; nt < 14; ++nt) {
                    int ry = nt >> 1, cb = nt & 1;
                    int y_in = 2 * ry + dyky;
                    int x_in = cb ? xc1 : xc0;
                    int blk = bi ^ (x_in & 7);
                    s16x8 B = *(const s16x8*)&xs2[((y_in * 16 + x_in) * 8 + blk) * 8];
                    acc[nt] = __builtin_amdgcn_mfma_f32_16x16x32_bf16(A, B, acc[nt], 0, 0, 0);
                }
            }
        }

        // epilogue: affine -> pool (shfl 1,8) -> ReLU -> store into xs3 (swizzled)
        int m = lx >> 1;
        bool keep = (dy == 0) && ((lx & 1) == 0);
        int oc0 = wid * 16 + quad * 4;
        float2 abv[4];
#pragma unroll
        for (int r = 0; r < 4; ++r) abv[r] = ab2[oc0 + r];
#pragma unroll
        for (int nt = 0; nt < 14; ++nt) {
            int ry = nt >> 1, cb = nt & 1;
            int xp = cb * 4 + m;
            float pv[4];
#pragma unroll
            for (int r = 0; r < 4; ++r) {
                float v = acc[nt][r] * abv[r].x + abv[r].y;
                v = fmaxf(v, __shfl_xor(v, 1));
                v = fmaxf(v, __shfl_xor(v, 8));
                pv[r] = fmaxf(v, 0.f);
            }
            if (keep && xp < 7) {
                uint2 pk;
                pk.x = (unsigned)f2bfu(pv[0]) | ((unsigned)f2bfu(pv[1]) << 16);
                pk.y = (unsigned)f2bfu(pv[2]) | ((unsigned)f2bfu(pv[3]) << 16);
                int blk3 = (oc0 >> 3) ^ (((xp + 1) & 7) << 1);
                *(uint2*)&xs3[(((ry + 1) * 8 + (xp + 1)) * 16 + blk3) * 8 + (oc0 & 7)] = pk;
            }
        }
    }
    __syncthreads();

    // ---- stage C: conv3 (128->256) via MFMA + BN + ReLU + pool + fc1[row1] dot ----
    f32x4 acc[2][3];                         // 2 oc-tiles per wave (8 waves x 2 = 16 tiles = 256 oc)
    f32x4 z = {0.f, 0.f, 0.f, 0.f};
#pragma unroll
    for (int ml = 0; ml < 2; ++ml)
#pragma unroll
        for (int nt = 0; nt < 3; ++nt) acc[ml][nt] = z;

#pragma unroll 1
    for (int kykx = 0; kykx < 9; ++kykx) {
        int ky = kykx / 3, kx = kykx - 3 * ky;
        int dyky = dy + ky;
        int x_in = lx + kx; if (x_in > 7) x_in = 7;   // lanes lx>=6 discarded later
#pragma unroll
        for (int kk = 0; kk < 4; ++kk) {
            s16x8 A[2];
#pragma unroll
            for (int ml = 0; ml < 2; ++ml)
                A[ml] = *(const s16x8*)(wT3 + ((kykx * 256 + (wid * 2 + ml) * 16 + n16) * 128 + kk * 32 + quad * 8));
            int bi = kk * 4 + quad;
            int blk = bi ^ ((x_in & 7) << 1);
#pragma unroll
            for (int nt = 0; nt < 3; ++nt) {
                int y_in = 2 * nt + dyky;
                s16x8 B = *(const s16x8*)&xs3[((y_in * 8 + x_in) * 16 + blk) * 8];
#pragma unroll
                for (int ml = 0; ml < 2; ++ml)
                    acc[ml][nt] = __builtin_amdgcn_mfma_f32_16x16x32_bf16(A[ml], B, acc[ml][nt], 0, 0, 0);
            }
        }
    }
    __syncthreads();                         // all xs3 reads done -> u3 reusable as red

    // epilogue: affine -> pool -> relu -> dot with fc1_w row 1
    float vacc = 0.f;
    int m = lx >> 1;
    bool keep = (dy == 0) && ((lx & 1) == 0) && (m < 3);
    const float* fc1w1 = fc1w + 2304;        // row 1 (only row that matters)
#pragma unroll
    for (int ml = 0; ml < 2; ++ml) {
        int oc0 = (wid * 2 + ml) * 16 + quad * 4;
        float2 abv[4];
#pragma unroll
        for (int r = 0; r < 4; ++r) abv[r] = ab3[oc0 + r];
#pragma unroll
        for (int nt = 0; nt < 3; ++nt) {
#pragma unroll
            for (int r = 0; r < 4; ++r) {
                float v = acc[ml][nt][r] * abv[r].x + abv[r].y;
                v = fmaxf(v, __shfl_xor(v, 1));
                v = fmaxf(v, __shfl_xor(v, 8));
                v = fmaxf(v, 0.f);
                if (keep) vacc += v * fc1w1[(oc0 + r) * 9 + nt * 3 + m];
            }
        }
    }
#pragma unroll
    for (int s = 1; s < 64; s <<= 1) vacc += __shfl_xor(vacc, s);
    if (lane == 0) red[wid] = vacc;
    __syncthreads();
    if (t == 0) {
        float v = red[0] + red[1] + red[2] + red[3]
                + red[4] + red[5] + red[6] + red[7] + qc[5];
        // quantum circuit closed form: <Z0 Z1> = cos(h[:,1]) * cos(qp[1])
        float q = cosf(v) * qc[4];
        float l0 = q * qc[0] + qc[2];
        float l1 = q * qc[1] + qc[3];
        float mx = fmaxf(l0, l1);
        float lse = mx + logf(__expf(l0 - mx) + __expf(l1 - mx));
        out[b * 2 + 0] = l0 - lse;
        out[b * 2 + 1] = l1 - lse;
    }
}

extern "C" void kernel_launch(void* const* d_in, const int* in_sizes, int n_in,
                              void* d_out, int out_size, void* d_ws, size_t ws_size,
                              hipStream_t stream)
{
    const float* x    = (const float*)d_in[0];
    const float* c1w  = (const float*)d_in[1];
    const float* c1b  = (const float*)d_in[2];
    const float* c2w  = (const float*)d_in[3];
    const float* c2b  = (const float*)d_in[4];
    const float* c3w  = (const float*)d_in[5];
    const float* c3b  = (const float*)d_in[6];
    const float* g1   = (const float*)d_in[7];
    const float* b1   = (const float*)d_in[8];
    const float* m1   = (const float*)d_in[9];
    const float* v1   = (const float*)d_in[10];
    const float* g2   = (const float*)d_in[11];
    const float* b2   = (const float*)d_in[12];
    const float* m2   = (const float*)d_in[13];
    const float* v2   = (const float*)d_in[14];
    const float* g3   = (const float*)d_in[15];
    const float* b3   = (const float*)d_in[16];
    const float* m3   = (const float*)d_in[17];
    const float* v3   = (const float*)d_in[18];
    const float* fc1w = (const float*)d_in[19];
    const float* fc1b = (const float*)d_in[20];
    const float* qp   = (const float*)d_in[21];
    const float* fc2w = (const float*)d_in[22];
    const float* fc2b = (const float*)d_in[23];
    const float* fc3w = (const float*)d_in[24];
    const float* fc3b = (const float*)d_in[25];
    float* out = (float*)d_out;
    char* ws = (char*)d_ws;

    short*  wT2 = (short*)(ws + OFF_W2);
    short*  wT3 = (short*)(ws + OFF_W3);
    float2* ab1 = (float2*)(ws + OFF_AB1);
    float2* ab2 = (float2*)(ws + OFF_AB2);
    float2* ab3 = (float2*)(ws + OFF_AB3);
    float*  qc  = (float*)(ws + OFF_Q);

    int B = in_sizes[0] / 784;               // 8192

    prep_k<<<1152, 256, 0, stream>>>(c2w, c3w, c1b, g1, b1, m1, v1,
                                     c2b, g2, b2, m2, v2, c3b, g3, b3, m3, v3,
                                     fc1b, qp, fc2w, fc2b, fc3w, fc3b,
                                     wT2, wT3, ab1, ab2, ab3, qc);
    fused_k<<<B, 512, 0, stream>>>(x, c1w, ab1, ab2, ab3, wT2, wT3, fc1w, qc, out);
}

// Round 16
// 921.213 us; speedup vs baseline: 1.3997x; 1.0213x over previous
//
#include <hip/hip_runtime.h>
#include <hip/hip_bf16.h>
#include <math.h>

typedef float f32x4 __attribute__((ext_vector_type(4)));
typedef float f32x2 __attribute__((ext_vector_type(2)));
typedef short s16x8 __attribute__((ext_vector_type(8)));

// ---- workspace layout (bytes) ---- total < 1 MB
static const long long OFF_W2  = 0LL;        // bf16 [9][128][64]  = 147,456 B
static const long long OFF_W3  = 147456LL;   // bf16 [9][256][128] = 589,824 B
static const long long OFF_AB1 = 737280LL;   // float2 [64]
static const long long OFF_AB2 = 737792LL;   // float2 [128]
static const long long OFF_AB3 = 738816LL;   // float2 [256]
static const long long OFF_Q   = 740864LL;   // float  [8]: A0,A1,C0,C1,cos(qp1),fc1b1

__device__ inline unsigned short f2bfu(float f) {
    __hip_bfloat16 h = __float2bfloat16(f);
    unsigned short u;
    __builtin_memcpy(&u, &h, 2);
    return u;
}

// ---------------- prep: weight transpose to [kykx][oc][ic] bf16 + BN folding + fc fold ----------------
__global__ __launch_bounds__(256) void prep_k(
    const float* __restrict__ c2w, const float* __restrict__ c3w,
    const float* __restrict__ c1b, const float* __restrict__ g1, const float* __restrict__ b1,
    const float* __restrict__ m1, const float* __restrict__ v1,
    const float* __restrict__ c2b, const float* __restrict__ g2, const float* __restrict__ b2,
    const float* __restrict__ m2, const float* __restrict__ v2,
    const float* __restrict__ c3b, const float* __restrict__ g3, const float* __restrict__ b3,
    const float* __restrict__ m3, const float* __restrict__ v3,
    const float* __restrict__ fc1b, const float* __restrict__ qp,
    const float* __restrict__ fc2w, const float* __restrict__ fc2b,
    const float* __restrict__ fc3w, const float* __restrict__ fc3b,
    short* __restrict__ wT2, short* __restrict__ wT3,
    float2* __restrict__ ab1, float2* __restrict__ ab2, float2* __restrict__ ab3,
    float* __restrict__ qc)
{
    int tid = blockIdx.x * 256 + threadIdx.x;
    if (tid < 73728) {                       // 9*128*64
        int ic = tid & 63, oc = (tid >> 6) & 127, k = tid >> 13;
        wT2[tid] = (short)f2bfu(c2w[(oc * 64 + ic) * 9 + k]);
    }
    if (tid < 294912) {                      // 9*256*128
        int ic = tid & 127, oc = (tid >> 7) & 255, k = tid >> 15;
        wT3[tid] = (short)f2bfu(c3w[(oc * 128 + ic) * 9 + k]);
    }
    if (tid < 64) {
        float s = g1[tid] / sqrtf(v1[tid] + 1e-5f);
        ab1[tid] = make_float2(s, (c1b[tid] - m1[tid]) * s + b1[tid]);
    } else if (tid < 192) {
        int c = tid - 64;
        float s = g2[c] / sqrtf(v2[c] + 1e-5f);
        ab2[c] = make_float2(s, (c2b[c] - m2[c]) * s + b2[c]);
    } else if (tid < 448) {
        int c = tid - 192;
        float s = g3[c] / sqrtf(v3[c] + 1e-5f);
        ab3[c] = make_float2(s, (c3b[c] - m3[c]) * s + b3[c]);
    } else if (tid == 448) {
        float A0 = 0.f, A1 = 0.f, B0 = 0.f, B1 = 0.f;
        for (int k = 0; k < 128; ++k) {
            float f2 = fc2w[k], fb = fc2b[k];
            A0 += fc3w[k] * f2;        B0 += fc3w[k] * fb;
            A1 += fc3w[128 + k] * f2;  B1 += fc3w[128 + k] * fb;
        }
        qc[0] = A0; qc[1] = A1;
        qc[2] = B0 + fc3b[0]; qc[3] = B1 + fc3b[1];
        qc[4] = cosf(qp[1]);  qc[5] = fc1b[1];
    }
}

// ---------------- fused: R15 structure + f32x2-packed conv1 ----------------
// R15 base (R12's 48 KB LDS union, (512,6) -> 3 blocks/CU, low-pressure 2-oc stage A,
// single-pass conv2 acc[14], halo-only prologue + x-prefetch; rocprof-dispatch best 955us).
// ONE change: stage-A conv1 FMAs packed into f32x2 (v_pk_fma_f32 dual-issue) -- the exact
// R4-R7 formulation (proven correct) transplanted into the 2-oc-group structure. Halves the
// 882/thread scalar FMA stream; stage A is ~20% of the block critical path, VALU is the
// largest pipe at 41.5%.
__global__ __launch_bounds__(512, 6) void fused_k(
    const float* __restrict__ x, const float* __restrict__ c1w,
    const float2* __restrict__ ab1, const float2* __restrict__ ab2,
    const float2* __restrict__ ab3,
    const short* __restrict__ wT2, const short* __restrict__ wT3,
    const float* __restrict__ fc1w, const float* __restrict__ qc,
    float* __restrict__ out)
{
    __shared__ short xs2[16 * 16 * 64];      // conv2 input tile [y][x][8 blk][8 ic], swizzled (32 KB)
    __shared__ short u3[8 * 8 * 128];        // 16 KB UNION: stage-A xt / conv3 xs3 / final red

    float (*xt)[32] = (float (*)[32])u3;     // padded 28x28 input at [1..28][1..28]
    short* xs3 = u3;                         // conv3 input tile [y][x][16 blk][8 ic], swizzled
    float* red = (float*)u3;                 // 8 floats, valid only after post-conv3 barrier

    int b = blockIdx.x, t = threadIdx.x;

    // ---- prefetch input (latency hides under halo zeroing) ----
    float xv0 = x[b * 784 + t];              // t < 512 < 784: always valid
    float xv1 = (t + 512 < 784) ? x[b * 784 + t + 512] : 0.f;

    // ---- halo-only zero-init ----
    // xs2 halo: positions with y in {0,15} or x in {0,15} -> 60 pos x 32 u32 = 1920 u32.
    for (int i = t; i < 1920; i += 512) {
        int pos = i >> 5, w = i & 31;
        int yy, xx;
        if (pos < 16)      { yy = 0;  xx = pos; }
        else if (pos < 32) { yy = 15; xx = pos - 16; }
        else { int q = pos - 32; yy = 1 + (q >> 1); xx = (q & 1) ? 15 : 0; }
        ((unsigned*)xs2)[(yy * 16 + xx) * 32 + w] = 0u;
    }
    // xt halo: row 0 (32), row 29 (32), col 0 rows 1..28 (28), col 29 rows 1..28 (28) = 120 floats.
    if (t < 120) {
        int yy, xx;
        if (t < 32)      { yy = 0;  xx = t; }
        else if (t < 64) { yy = 29; xx = t - 32; }
        else if (t < 92) { yy = 1 + (t - 64); xx = 0; }
        else             { yy = 1 + (t - 92); xx = 29; }
        xt[yy][xx] = 0.f;
    }
    __syncthreads();

    // ---- stage A: store input, load conv1 weights ----
    xt[t / 28 + 1][t % 28 + 1] = xv0;
    if (t + 512 < 784) xt[(t + 512) / 28 + 1][(t + 512) % 28 + 1] = xv1;

    int ocg2 = t & 31;                       // 32 groups of 2 output channels
    float wr[2][9];
    float2 abr[2];
#pragma unroll
    for (int c = 0; c < 2; ++c) {
#pragma unroll
        for (int k = 0; k < 9; ++k) wr[c][k] = c1w[(ocg2 * 2 + c) * 9 + k];
        abr[c] = ab1[ocg2 * 2 + c];
    }
    __syncthreads();

    int posb = t >> 5;                       // 0..15
    for (int p = posb; p < 196; p += 16) {
        int py = p / 14, px = p % 14;
        int y0 = 2 * py, x0 = 2 * px;
        float patch[4][4];
#pragma unroll
        for (int i = 0; i < 4; ++i)
#pragma unroll
            for (int j = 0; j < 4; ++j) patch[i][j] = xt[y0 + i][x0 + j];

        unsigned short ub[2];
#pragma unroll
        for (int c = 0; c < 2; ++c) {
            f32x2 r0 = {0.f, 0.f};           // (a00, a01)
            f32x2 r1 = {0.f, 0.f};           // (a10, a11)
#pragma unroll
            for (int ky = 0; ky < 3; ++ky)
#pragma unroll
                for (int kx = 0; kx < 3; ++kx) {
                    float wv = wr[c][ky * 3 + kx];
                    f32x2 p0 = {patch[ky + 0][kx], patch[ky + 0][kx + 1]};
                    f32x2 p1 = {patch[ky + 1][kx], patch[ky + 1][kx + 1]};
                    r0 += p0 * wv;
                    r1 += p1 * wv;
                }
            float aa = abr[c].x, bb = abr[c].y;
            f32x2 s0 = r0 * aa + bb;
            f32x2 s1 = r1 * aa + bb;
            float v = fmaxf(fmaxf(s0.x, s0.y), fmaxf(s1.x, s1.y));
            ub[c] = f2bfu(fmaxf(v, 0.f));
        }
        unsigned pk = (unsigned)ub[0] | ((unsigned)ub[1] << 16);
        int oc0 = ocg2 * 2;                  // ic-group g = oc0>>3 = ocg2>>2; within-block = oc0&7
        int blk = (ocg2 >> 2) ^ ((px + 1) & 7);   // XOR swizzle by padded column
        *(unsigned*)&xs2[((((py + 1) * 16) + (px + 1)) * 8 + blk) * 8 + (oc0 & 7)] = pk;
    }
    __syncthreads();
    // xt is DEAD; u3 becomes xs3. Zero only the halo (row 0 cols 0..7, col 0 rows 1..7).
    for (int i = t; i < 960; i += 512) {     // 15 pos x 64 u32
        int pos = i >> 6, w = i & 63;
        int yy = (pos < 8) ? 0 : pos - 7;
        int xx = (pos < 8) ? pos : 0;
        ((unsigned*)xs3)[(yy * 8 + xx) * 64 + w] = 0u;
    }

    // ---- stage B: conv2 (64->128) via MFMA + BN + ReLU + pool -> xs3 (single pass, acc[14]) ----
    int lane = t & 63, wid = t >> 6;         // wid 0..7, one 16-oc tile per wave
    int quad = lane >> 4, n16 = lane & 15;
    int dy = n16 >> 3, lx = n16 & 7;

    {
        f32x4 acc[14];
        f32x4 z = {0.f, 0.f, 0.f, 0.f};
#pragma unroll
        for (int nt = 0; nt < 14; ++nt) acc[nt] = z;

#pragma unroll 1
        for (int kykx = 0; kykx < 9; ++kykx) {
            int ky = kykx / 3, kx = kykx - 3 * ky;
            int dyky = dy + ky;
            int xc0 = lx + kx;                       // padded col, cb=0
            int xc1 = xc0 + 8; if (xc1 > 15) xc1 = 15;  // cb=1; lanes lx>=6 discarded later
#pragma unroll
            for (int kk = 0; kk < 2; ++kk) {
                s16x8 A = *(const s16x8*)(wT2 + ((kykx * 128 + wid * 16 + n16) * 64 + kk * 32 + quad * 8));
                int bi = kk * 4 + quad;
#pragma unroll
                for (int nt = 0; nt < 14; ++nt) {
                    int ry = nt >> 1, cb = nt & 1;
                    int y_in = 2 * ry + dyky;
                    int x_in = cb ? xc1 : xc0;
                    int blk = bi ^ (x_in & 7);
                    s16x8 B = *(const s16x8*)&xs2[((y_in * 16 + x_in) * 8 + blk) * 8];
                    acc[nt] = __builtin_amdgcn_mfma_f32_16x16x32_bf16(A, B, acc[nt], 0, 0, 0);
                }
            }
        }

        // epilogue: affine -> pool (shfl 1,8) -> ReLU -> store into xs3 (swizzled)
        int m = lx >> 1;
        bool keep = (dy == 0) && ((lx & 1) == 0);
        int oc0 = wid * 16 + quad * 4;
        float2 abv[4];
#pragma unroll
        for (int r = 0; r < 4; ++r) abv[r] = ab2[oc0 + r];
#pragma unroll
        for (int nt = 0; nt < 14; ++nt) {
            int ry = nt >> 1, cb = nt & 1;
            int xp = cb * 4 + m;
            float pv[4];
#pragma unroll
            for (int r = 0; r < 4; ++r) {
                float v = acc[nt][r] * abv[r].x + abv[r].y;
                v = fmaxf(v, __shfl_xor(v, 1));
                v = fmaxf(v, __shfl_xor(v, 8));
                pv[r] = fmaxf(v, 0.f);
            }
            if (keep && xp < 7) {
                uint2 pk;
                pk.x = (unsigned)f2bfu(pv[0]) | ((unsigned)f2bfu(pv[1]) << 16);
                pk.y = (unsigned)f2bfu(pv[2]) | ((unsigned)f2bfu(pv[3]) << 16);
                int blk3 = (oc0 >> 3) ^ (((xp + 1) & 7) << 1);
                *(uint2*)&xs3[(((ry + 1) * 8 + (xp + 1)) * 16 + blk3) * 8 + (oc0 & 7)] = pk;
            }
        }
    }
    __syncthreads();

    // ---- stage C: conv3 (128->256) via MFMA + BN + ReLU + pool + fc1[row1] dot ----
    f32x4 acc[2][3];                         // 2 oc-tiles per wave (8 waves x 2 = 16 tiles = 256 oc)
    f32x4 z = {0.f, 0.f, 0.f, 0.f};
#pragma unroll
    for (int ml = 0; ml < 2; ++ml)
#pragma unroll
        for (int nt = 0; nt < 3; ++nt) acc[ml][nt] = z;

#pragma unroll 1
    for (int kykx = 0; kykx < 9; ++kykx) {
        int ky = kykx / 3, kx = kykx - 3 * ky;
        int dyky = dy + ky;
        int x_in = lx + kx; if (x_in > 7) x_in = 7;   // lanes lx>=6 discarded later
#pragma unroll
        for (int kk = 0; kk < 4; ++kk) {
            s16x8 A[2];
#pragma unroll
            for (int ml = 0; ml < 2; ++ml)
                A[ml] = *(const s16x8*)(wT3 + ((kykx * 256 + (wid * 2 + ml) * 16 + n16) * 128 + kk * 32 + quad * 8));
            int bi = kk * 4 + quad;
            int blk = bi ^ ((x_in & 7) << 1);
#pragma unroll
            for (int nt = 0; nt < 3; ++nt) {
                int y_in = 2 * nt + dyky;
                s16x8 B = *(const s16x8*)&xs3[((y_in * 8 + x_in) * 16 + blk) * 8];
#pragma unroll
                for (int ml = 0; ml < 2; ++ml)
                    acc[ml][nt] = __builtin_amdgcn_mfma_f32_16x16x32_bf16(A[ml], B, acc[ml][nt], 0, 0, 0);
            }
        }
    }
    __syncthreads();                         // all xs3 reads done -> u3 reusable as red

    // epilogue: affine -> pool -> relu -> dot with fc1_w row 1
    float vacc = 0.f;
    int m = lx >> 1;
    bool keep = (dy == 0) && ((lx & 1) == 0) && (m < 3);
    const float* fc1w1 = fc1w + 2304;        // row 1 (only row that matters)
#pragma unroll
    for (int ml = 0; ml < 2; ++ml) {
        int oc0 = (wid * 2 + ml) * 16 + quad * 4;
        float2 abv[4];
#pragma unroll
        for (int r = 0; r < 4; ++r) abv[r] = ab3[oc0 + r];
#pragma unroll
        for (int nt = 0; nt < 3; ++nt) {
#pragma unroll
            for (int r = 0; r < 4; ++r) {
                float v = acc[ml][nt][r] * abv[r].x + abv[r].y;
                v = fmaxf(v, __shfl_xor(v, 1));
                v = fmaxf(v, __shfl_xor(v, 8));
                v = fmaxf(v, 0.f);
                if (keep) vacc += v * fc1w1[(oc0 + r) * 9 + nt * 3 + m];
            }
        }
    }
#pragma unroll
    for (int s = 1; s < 64; s <<= 1) vacc += __shfl_xor(vacc, s);
    if (lane == 0) red[wid] = vacc;
    __syncthreads();
    if (t == 0) {
        float v = red[0] + red[1] + red[2] + red[3]
                + red[4] + red[5] + red[6] + red[7] + qc[5];
        // quantum circuit closed form: <Z0 Z1> = cos(h[:,1]) * cos(qp[1])
        float q = cosf(v) * qc[4];
        float l0 = q * qc[0] + qc[2];
        float l1 = q * qc[1] + qc[3];
        float mx = fmaxf(l0, l1);
        float lse = mx + logf(__expf(l0 - mx) + __expf(l1 - mx));
        out[b * 2 + 0] = l0 - lse;
        out[b * 2 + 1] = l1 - lse;
    }
}

extern "C" void kernel_launch(void* const* d_in, const int* in_sizes, int n_in,
                              void* d_out, int out_size, void* d_ws, size_t ws_size,
                              hipStream_t stream)
{
    const float* x    = (const float*)d_in[0];
    const float* c1w  = (const float*)d_in[1];
    const float* c1b  = (const float*)d_in[2];
    const float* c2w  = (const float*)d_in[3];
    const float* c2b  = (const float*)d_in[4];
    const float* c3w  = (const float*)d_in[5];
    const float* c3b  = (const float*)d_in[6];
    const float* g1   = (const float*)d_in[7];
    const float* b1   = (const float*)d_in[8];
    const float* m1   = (const float*)d_in[9];
    const float* v1   = (const float*)d_in[10];
    const float* g2   = (const float*)d_in[11];
    const float* b2   = (const float*)d_in[12];
    const float* m2   = (const float*)d_in[13];
    const float* v2   = (const float*)d_in[14];
    const float* g3   = (const float*)d_in[15];
    const float* b3   = (const float*)d_in[16];
    const float* m3   = (const float*)d_in[17];
    const float* v3   = (const float*)d_in[18];
    const float* fc1w = (const float*)d_in[19];
    const float* fc1b = (const float*)d_in[20];
    const float* qp   = (const float*)d_in[21];
    const float* fc2w = (const float*)d_in[22];
    const float* fc2b = (const float*)d_in[23];
    const float* fc3w = (const float*)d_in[24];
    const float* fc3b = (const float*)d_in[25];
    float* out = (float*)d_out;
    char* ws = (char*)d_ws;

    short*  wT2 = (short*)(ws + OFF_W2);
    short*  wT3 = (short*)(ws + OFF_W3);
    float2* ab1 = (float2*)(ws + OFF_AB1);
    float2* ab2 = (float2*)(ws + OFF_AB2);
    float2* ab3 = (float2*)(ws + OFF_AB3);
    float*  qc  = (float*)(ws + OFF_Q);

    int B = in_sizes[0] / 784;               // 8192

    prep_k<<<1152, 256, 0, stream>>>(c2w, c3w, c1b, g1, b1, m1, v1,
                                     c2b, g2, b2, m2, v2, c3b, g3, b3, m3, v3,
                                     fc1b, qp, fc2w, fc2b, fc3w, fc3b,
                                     wT2, wT3, ab1, ab2, ab3, qc);
    fused_k<<<B, 512, 0, stream>>>(x, c1w, ab1, ab2, ab3, wT2, wT3, fc1w, qc, out);
}